// Round 2
// baseline (213.762 us; speedup 1.0000x reference)
//
#include <hip/hip_runtime.h>
#include <hip/hip_bf16.h>

typedef __bf16 bf16x8 __attribute__((ext_vector_type(8)));
typedef short short8 __attribute__((ext_vector_type(8)));
typedef float f32x4 __attribute__((ext_vector_type(4)));
typedef unsigned short ushort_t;

#define T_LEN 32768
#define B_SZ 4
#define NSLOW 2047
#define NSEQ (B_SZ * NSLOW)   // 8188
#define GH 64
#define G3 192
#define NL 4
#define HID 32
#define L2E 1.44269504088896341f

// staging-buffer (bf16) element offsets, concatenated in input order
#define OFF_X    0
#define OFF_FCW  131072
#define OFF_FCB  131136
#define OFF_WIH  131200
#define OFF_WHH  180352
#define OFF_BIH  229504
#define OFF_BHH  230272
#define OFF_OFW  231040
#define OFF_OFB  235136
#define OFF_FINW 235200
#define OFF_FINB 235232
#define OFF_FOW  235264
#define OFF_FOB  235296
#define CONV_TOTAL 235297
#define CONV_PAD_BYTES 470656   // 16B-aligned end of staging region

static __device__ __forceinline__ float bf2f(ushort_t u) {
    union { unsigned u; float f; } c; c.u = ((unsigned)u) << 16; return c.f;
}
static __device__ __forceinline__ ushort_t f2bf(float f) {
    union { float f; unsigned u; } c; c.f = f;
    unsigned r = (c.u + 0x7FFFu + ((c.u >> 16) & 1u)) >> 16;
    return (ushort_t)r;
}
static __device__ __forceinline__ f32x4 mfma16(short8 a, short8 b, f32x4 c) {
    return __builtin_amdgcn_mfma_f32_16x16x32_bf16(
        __builtin_bit_cast(bf16x8, a), __builtin_bit_cast(bf16x8, b), c, 0, 0, 0);
}
// LDS layout: element off = ((t*8 + kb)*16 + (seq ^ ((kb&3)<<2)))*8 + i
static __device__ __forceinline__ int xoff(int t, int kb, int seq) {
    return ((((t << 3) + kb) << 4) + (seq ^ ((kb & 3) << 2))) << 3;
}
static __device__ __forceinline__ short8 load_frag_scaled(const ushort_t* p, float s) {
    uint4 r = *(const uint4*)p;
    unsigned aa[4] = {r.x, r.y, r.z, r.w};
    short8 o;
#pragma unroll
    for (int i = 0; i < 4; ++i) {
        o[2 * i]     = (short)f2bf(bf2f((ushort_t)(aa[i] & 0xffffu)) * s);
        o[2 * i + 1] = (short)f2bf(bf2f((ushort_t)(aa[i] >> 16)) * s);
    }
    return o;
}

// ---------------- K0: dtype detector ----------------
// bf16 N(0,1)-ish data: nearly all exponent fields in [80,141].
// f32 read as ushorts: every low half-word has a uniform-random exponent
// field -> only ~62% of words look sane. Count over 256 words, threshold 224.
__global__ __launch_bounds__(64) void detect_kernel(const ushort_t* __restrict__ x,
                                                    int* __restrict__ flag)
{
    int lane = threadIdx.x;
    int cnt = 0;
#pragma unroll
    for (int i = 0; i < 4; ++i) {
        ushort_t u = x[lane * 4 + i];
        int e = (u >> 7) & 0xFF;
        if (e >= 80 && e <= 141) cnt++;
    }
#pragma unroll
    for (int d = 1; d < 64; d <<= 1) cnt += __shfl_xor(cnt, d, 64);
    if (lane == 0) *flag = (cnt >= 224) ? 1 : 0;   // 1 = inputs are bf16
}

// ---------------- K0.5: stage all inputs as bf16 ----------------
struct Ptrs13 { const void* p[13]; };

__global__ __launch_bounds__(256) void convert_kernel(Ptrs13 ptrs,
                                                      const int* __restrict__ flag,
                                                      ushort_t* __restrict__ dst)
{
    const int offs[14] = {OFF_X, OFF_FCW, OFF_FCB, OFF_WIH, OFF_WHH, OFF_BIH,
                          OFF_BHH, OFF_OFW, OFF_OFB, OFF_FINW, OFF_FINB,
                          OFF_FOW, OFF_FOB, CONV_TOTAL};
    const bool isbf = (*flag != 0);
    for (int idx = blockIdx.x * 256 + threadIdx.x; idx < CONV_TOTAL;
         idx += gridDim.x * 256) {
        int s = 0;
#pragma unroll
        for (int j = 1; j < 13; ++j) if (idx >= offs[j]) s = j;
        int k = idx - offs[s];
        ushort_t v = isbf ? ((const ushort_t*)ptrs.p[s])[k]
                          : f2bf(((const float*)ptrs.p[s])[k]);
        dst[idx] = v;
    }
}

// ---------------- K1: fused 4-layer GRU + out-FC + sigmoid ----------------
__global__ __launch_bounds__(256) void gru_kernel(
    const ushort_t* __restrict__ x, const ushort_t* __restrict__ fcw,
    const ushort_t* __restrict__ fcb, const ushort_t* __restrict__ wih,
    const ushort_t* __restrict__ whh, const ushort_t* __restrict__ bih,
    const ushort_t* __restrict__ bhh, const ushort_t* __restrict__ ofw,
    const ushort_t* __restrict__ ofb, float* __restrict__ Aslow,
    float* __restrict__ gslow)
{
    __shared__ short8 Xs8[4096];   // 64 KB: 16 seq x 32 t x 64 feat, swizzled
    short* Xs = (short*)Xs8;
    const int tid = threadIdx.x;
    const int w = tid >> 6, lane = tid & 63;
    const int q = lane >> 4, m = lane & 15;
    const int jb = w * 16;
    const int n0 = blockIdx.x * 16;

    // ---- fill layer-0 input: relu(x_s * fc_in_w + fc_in_b) ----
#pragma unroll 1
    for (int ii = 0; ii < 16; ++ii) {
        int cid = ii * 256 + tid;
        int seq = cid & 15, kb = (cid >> 4) & 7, t = cid >> 7;
        int n = n0 + seq; if (n > NSEQ - 1) n = NSEQ - 1;
        int b = n / NSLOW, s = n - b * NSLOW;
        float xv = bf2f(x[b * T_LEN + s * 16 + t]);
        short8 v;
#pragma unroll
        for (int i = 0; i < 8; ++i) {
            int g = kb * 8 + i;
            float h = fmaf(xv, bf2f(fcw[g]), bf2f(fcb[g]));
            h = h > 0.f ? h : 0.f;
            v[i] = (short)f2bf(h);
        }
        Xs8[xoff(t, kb, seq) >> 3] = v;
    }

    const int kb_w = 2 * w + (m >> 3);     // write-side feature block
    const int i7 = m & 7;
    const int wsz = (kb_w & 3) << 2;
    const int colR = jb + m;               // this wave's hidden-unit column

    float hc[4];
#pragma unroll 1
    for (int l = 0; l < NL; ++l) {
        const ushort_t* wl = wih + l * G3 * GH;
        const ushort_t* ul = whh + l * G3 * GH;
        const int kofs = q * 8;
        short8 wR0 = load_frag_scaled(wl + (0 * 64 + colR) * 64 + kofs, -L2E);
        short8 wR1 = load_frag_scaled(wl + (0 * 64 + colR) * 64 + 32 + kofs, -L2E);
        short8 wZ0 = load_frag_scaled(wl + (1 * 64 + colR) * 64 + kofs, -L2E);
        short8 wZ1 = load_frag_scaled(wl + (1 * 64 + colR) * 64 + 32 + kofs, -L2E);
        short8 wN0 = load_frag_scaled(wl + (2 * 64 + colR) * 64 + kofs, 2.f * L2E);
        short8 wN1 = load_frag_scaled(wl + (2 * 64 + colR) * 64 + 32 + kofs, 2.f * L2E);
        short8 uR0 = load_frag_scaled(ul + (0 * 64 + colR) * 64 + kofs, -L2E);
        short8 uR1 = load_frag_scaled(ul + (0 * 64 + colR) * 64 + 32 + kofs, -L2E);
        short8 uZ0 = load_frag_scaled(ul + (1 * 64 + colR) * 64 + kofs, -L2E);
        short8 uZ1 = load_frag_scaled(ul + (1 * 64 + colR) * 64 + 32 + kofs, -L2E);
        short8 uN0 = load_frag_scaled(ul + (2 * 64 + colR) * 64 + kofs, 2.f * L2E);
        short8 uN1 = load_frag_scaled(ul + (2 * 64 + colR) * 64 + 32 + kofs, 2.f * L2E);

        float bR  = -L2E * (bf2f(bih[l * G3 + colR]) + bf2f(bhh[l * G3 + colR]));
        float bZ  = -L2E * (bf2f(bih[l * G3 + 64 + colR]) + bf2f(bhh[l * G3 + 64 + colR]));
        float bNX = 2.f * L2E * bf2f(bih[l * G3 + 128 + colR]);
        float bNH = 2.f * L2E * bf2f(bhh[l * G3 + 128 + colR]);

        hc[0] = hc[1] = hc[2] = hc[3] = 0.f;

#pragma unroll 1
        for (int t = 0; t < 32; ++t) {
            __syncthreads();               // prev step's writes visible
            short8 ax0 = Xs8[xoff(t, q, m) >> 3];
            short8 ax1 = Xs8[xoff(t, 4 + q, m) >> 3];
            short8 ah0 = ax0, ah1 = ax1;
            if (t > 0) {
                ah0 = Xs8[xoff(t - 1, q, m) >> 3];
                ah1 = Xs8[xoff(t - 1, 4 + q, m) >> 3];
            }
            __syncthreads();               // reads done before in-place writes
            f32x4 aR  = {bR, bR, bR, bR};
            f32x4 aZ  = {bZ, bZ, bZ, bZ};
            f32x4 aNX = {bNX, bNX, bNX, bNX};
            f32x4 aNH = {bNH, bNH, bNH, bNH};
            aR  = mfma16(ax0, wR0, aR);  aR  = mfma16(ax1, wR1, aR);
            aZ  = mfma16(ax0, wZ0, aZ);  aZ  = mfma16(ax1, wZ1, aZ);
            aNX = mfma16(ax0, wN0, aNX); aNX = mfma16(ax1, wN1, aNX);
            if (t > 0) {
                aR  = mfma16(ah0, uR0, aR);  aR  = mfma16(ah1, uR1, aR);
                aZ  = mfma16(ah0, uZ0, aZ);  aZ  = mfma16(ah1, uZ1, aZ);
                aNH = mfma16(ah0, uN0, aNH); aNH = mfma16(ah1, uN1, aNH);
            }
#pragma unroll
            for (int i = 0; i < 4; ++i) {
                float r = __builtin_amdgcn_rcpf(1.f + __builtin_amdgcn_exp2f(aR[i]));
                float z = __builtin_amdgcn_rcpf(1.f + __builtin_amdgcn_exp2f(aZ[i]));
                float yp = fmaf(r, aNH[i], aNX[i]);
                float nn = fmaf(-2.f,
                    __builtin_amdgcn_rcpf(1.f + __builtin_amdgcn_exp2f(yp)), 1.f);
                hc[i] = fmaf(z, hc[i] - nn, nn);
                int seq = 4 * q + i;
                Xs[((((t << 3) + kb_w) << 4) + (seq ^ wsz)) * 8 + i7] =
                    (short)f2bf(hc[i]);
            }
        }
    }

    // ---- epilogue: eps = h_last @ out_fc_w^T + b ; A=sigmoid(eps[:32]) ----
    __syncthreads();
    short8 aL0 = Xs8[xoff(31, q, m) >> 3];
    short8 aL1 = Xs8[xoff(31, 4 + q, m) >> 3];
    const int colO = jb + m;
    float sc = (w < 2) ? -L2E : 1.f;
    short8 o0 = load_frag_scaled(ofw + colO * 64 + q * 8, sc);
    short8 o1 = load_frag_scaled(ofw + colO * 64 + 32 + q * 8, sc);
    float be = bf2f(ofb[colO]) * sc;
    f32x4 aE = {be, be, be, be};
    aE = mfma16(aL0, o0, aE);
    aE = mfma16(aL1, o1, aE);
#pragma unroll
    for (int i = 0; i < 4; ++i) {
        int n = n0 + 4 * q + i;   // ws regions sized 8192 rows, pad harmless
        if (w < 2)
            Aslow[n * HID + colO] =
                __builtin_amdgcn_rcpf(1.f + __builtin_amdgcn_exp2f(aE[i]));
        else
            gslow[n * HID + (colO - 32)] = aE[i];
    }
}

// ---------------- K2: per-chunk (prod A, partial sum) ----------------
__global__ __launch_bounds__(256) void pass1_kernel(
    const ushort_t* __restrict__ x, const float* __restrict__ Aslow,
    const float* __restrict__ gslow, const ushort_t* __restrict__ finw,
    const ushort_t* __restrict__ finb, float* __restrict__ P,
    float* __restrict__ S)
{
    int gt = blockIdx.x * 256 + threadIdx.x;    // 16384 = 4b * 128c * 32h
    int h = gt & 31, c = (gt >> 5) & 127, b = gt >> 12;
    float fw = bf2f(finw[h]), fb = bf2f(finb[h]);
    float Pv = 1.f, Sv = 0.f;
    int t0 = c * 256;
#pragma unroll 1
    for (int seg = 0; seg < 16; ++seg) {
        int sidx = (t0 >> 4) + seg - 1;
        if (sidx < 0) sidx = 0;
        if (sidx > NSLOW - 1) sidx = NSLOW - 1;   // (was NSLOW-2: bug)
        float A = Aslow[(b * NSLOW + sidx) * HID + h];
        float g = gslow[(b * NSLOW + sidx) * HID + h];
        float fwg = fw * g, fbg = fb * g;
        const uint4* px = (const uint4*)(x + b * T_LEN + t0 + seg * 16);
        uint4 ra = px[0], rb = px[1];
        unsigned xa[8] = {ra.x, ra.y, ra.z, ra.w, rb.x, rb.y, rb.z, rb.w};
#pragma unroll
        for (int j = 0; j < 8; ++j) {
            float x0 = bf2f((ushort_t)(xa[j] & 0xffffu));
            float x1 = bf2f((ushort_t)(xa[j] >> 16));
            Sv = fmaf(A, Sv, fmaf(x0, fwg, fbg));
            Sv = fmaf(A, Sv, fmaf(x1, fwg, fbg));
        }
        float A2 = A * A, A4 = A2 * A2, A8 = A4 * A4;
        Pv *= A8 * A8;
    }
    P[(b * HID + h) * 128 + c] = Pv;
    S[(b * HID + h) * 128 + c] = Sv;
}

// ---------------- K3: scan of chunk summaries ----------------
__global__ __launch_bounds__(128) void scan_kernel(
    const float* __restrict__ P, const float* __restrict__ S,
    float* __restrict__ Hpre)
{
    int tid = threadIdx.x;   // 128 = (b,h)
    const float4* p4 = (const float4*)(P + tid * 128);
    const float4* s4 = (const float4*)(S + tid * 128);
    float* hp = Hpre + tid * 128;
    float hr = 0.f;
#pragma unroll 1
    for (int c = 0; c < 32; ++c) {
        float4 pv = p4[c], sv = s4[c];
        hp[4 * c + 0] = hr; hr = fmaf(pv.x, hr, sv.x);
        hp[4 * c + 1] = hr; hr = fmaf(pv.y, hr, sv.y);
        hp[4 * c + 2] = hr; hr = fmaf(pv.z, hr, sv.z);
        hp[4 * c + 3] = hr; hr = fmaf(pv.w, hr, sv.w);
    }
}

// ---------------- K4: recompute states + fused output dot ----------------
__global__ __launch_bounds__(256) void pass2_kernel(
    const ushort_t* __restrict__ x, const float* __restrict__ Aslow,
    const float* __restrict__ gslow, const float* __restrict__ Hpre,
    const ushort_t* __restrict__ finw, const ushort_t* __restrict__ finb,
    const ushort_t* __restrict__ fow, const ushort_t* __restrict__ fob,
    const int* __restrict__ flag, void* __restrict__ outv)
{
    int wv = blockIdx.x * 4 + (threadIdx.x >> 6);   // 0..255
    int lane = threadIdx.x & 63;
    int half = lane >> 5, h = lane & 31;
    int pair = wv * 2 + half;                       // 0..511 = b*128 + c
    int b = pair >> 7, c = pair & 127;
    const bool isbf = (*flag != 0);
    ushort_t* outb = (ushort_t*)outv;
    float* outf = (float*)outv;
    float hv = Hpre[(b * HID + h) * 128 + c];
    float fw = bf2f(finw[h]), fb = bf2f(finb[h]);
    float wo = bf2f(fow[h]), ob = bf2f(fob[0]);
    int t0 = c * 256;
#pragma unroll 1
    for (int blk = 0; blk < 8; ++blk) {
        float ykeep = 0.f;
        float A = 0.f, fwg = 0.f, fbg = 0.f;
#pragma unroll
        for (int tt = 0; tt < 32; ++tt) {
            int t = t0 + blk * 32 + tt;
            if ((tt & 15) == 0) {
                int sidx = (t >> 4) - 1;
                if (sidx < 0) sidx = 0;
                A = Aslow[(b * NSLOW + sidx) * HID + h];
                float g = gslow[(b * NSLOW + sidx) * HID + h];
                fwg = fw * g; fbg = fb * g;
            }
            float xv = bf2f(x[b * T_LEN + t]);
            hv = fmaf(A, hv, fmaf(xv, fwg, fbg));
            float y = hv * wo;
            y += __shfl_xor(y, 1, 64);
            y += __shfl_xor(y, 2, 64);
            y += __shfl_xor(y, 4, 64);
            y += __shfl_xor(y, 8, 64);
            y += __shfl_xor(y, 16, 64);
            if (tt == h) ykeep = y + ob;
        }
        int oidx = b * T_LEN + t0 + blk * 32 + h;
        if (isbf) outb[oidx] = f2bf(ykeep);
        else      outf[oidx] = ykeep;
    }
}

extern "C" void kernel_launch(void* const* d_in, const int* in_sizes, int n_in,
                              void* d_out, int out_size, void* d_ws, size_t ws_size,
                              hipStream_t stream)
{
    // staged bf16 inputs live at the front of the workspace
    ushort_t* cv = (ushort_t*)d_ws;
    const ushort_t* x    = cv + OFF_X;
    const ushort_t* fcw  = cv + OFF_FCW;
    const ushort_t* fcb  = cv + OFF_FCB;
    const ushort_t* wih  = cv + OFF_WIH;
    const ushort_t* whh  = cv + OFF_WHH;
    const ushort_t* bih  = cv + OFF_BIH;
    const ushort_t* bhh  = cv + OFF_BHH;
    const ushort_t* ofw  = cv + OFF_OFW;
    const ushort_t* ofb  = cv + OFF_OFB;
    const ushort_t* finw = cv + OFF_FINW;
    const ushort_t* finb = cv + OFF_FINB;
    const ushort_t* fow  = cv + OFF_FOW;
    const ushort_t* fob  = cv + OFF_FOB;

    float* Aslow = (float*)((char*)d_ws + CONV_PAD_BYTES);  // 8192*32 f32
    float* gslow = Aslow + 8192 * 32;
    float* P     = gslow + 8192 * 32;
    float* S     = P + 16384;
    float* Hpre  = S + 16384;
    int*   flag  = (int*)(Hpre + 16384);

    Ptrs13 ptrs;
    for (int i = 0; i < 13; ++i) ptrs.p[i] = d_in[i];

    detect_kernel<<<dim3(1), dim3(64), 0, stream>>>((const ushort_t*)d_in[0], flag);
    convert_kernel<<<dim3(920), dim3(256), 0, stream>>>(ptrs, flag, cv);
    gru_kernel<<<dim3(512), dim3(256), 0, stream>>>(
        x, fcw, fcb, wih, whh, bih, bhh, ofw, ofb, Aslow, gslow);
    pass1_kernel<<<dim3(64), dim3(256), 0, stream>>>(
        x, Aslow, gslow, finw, finb, P, S);
    scan_kernel<<<dim3(1), dim3(128), 0, stream>>>(P, S, Hpre);
    pass2_kernel<<<dim3(64), dim3(256), 0, stream>>>(
        x, Aslow, gslow, Hpre, finw, finb, fow, fob, flag, d_out);
}

// Round 4
// 211.810 us; speedup vs baseline: 1.0092x; 1.0092x over previous
//
#include <hip/hip_runtime.h>
#include <hip/hip_bf16.h>

typedef __bf16 bf16x8 __attribute__((ext_vector_type(8)));
typedef short short8 __attribute__((ext_vector_type(8)));
typedef float f32x4 __attribute__((ext_vector_type(4)));
typedef unsigned short ushort_t;

#define T_LEN 32768
#define B_SZ 4
#define NSLOW 2047
#define NSEQ (B_SZ * NSLOW)   // 8188
#define GH 64
#define G3 192
#define NL 4
#define HID 32
#define NCH 256               // fast-path chunks per batch (len 128)
#define L2E 1.44269504088896341f

// staging-buffer (bf16) element offsets, concatenated in input order
#define OFF_X    0
#define OFF_FCW  131072
#define OFF_FCB  131136
#define OFF_WIH  131200
#define OFF_WHH  180352
#define OFF_BIH  229504
#define OFF_BHH  230272
#define OFF_OFW  231040
#define OFF_OFB  235136
#define OFF_FINW 235200
#define OFF_FINB 235232
#define OFF_FOW  235264
#define OFF_FOB  235296
#define CONV_TOTAL 235297
#define CONV_PAD_BYTES 470656   // 16B-aligned end of staging region

static __device__ __forceinline__ float bf2f(ushort_t u) {
    union { unsigned u; float f; } c; c.u = ((unsigned)u) << 16; return c.f;
}
static __device__ __forceinline__ ushort_t f2bf(float f) {
    union { float f; unsigned u; } c; c.f = f;
    unsigned r = (c.u + 0x7FFFu + ((c.u >> 16) & 1u)) >> 16;
    return (ushort_t)r;
}
static __device__ __forceinline__ unsigned pk2bf(float a, float b) {
    float2 f; f.x = a; f.y = b;
    __hip_bfloat162 h = __float22bfloat162_rn(f);   // v_cvt_pk_bf16_f32
    unsigned u;
    __builtin_memcpy(&u, &h, 4);
    return u;
}
static __device__ __forceinline__ f32x4 mfma16(short8 a, short8 b, f32x4 c) {
    return __builtin_amdgcn_mfma_f32_16x16x32_bf16(
        __builtin_bit_cast(bf16x8, a), __builtin_bit_cast(bf16x8, b), c, 0, 0, 0);
}
// LDS layout: short off = ((t*8 + kb)*16 + (seq ^ (kb&7)))*8 + i
// kb = feature>>3. Reads (lane m=seq, quad q -> kb=q / 4+q) hit distinct
// bank-quads per q -> 2-way (free). b64 h-writes ~4-way.
static __device__ __forceinline__ int xoff(int t, int kb, int seq) {
    return ((((t << 3) + kb) << 4) + (seq ^ (kb & 7))) << 3;
}
static __device__ __forceinline__ short8 load_frag_scaled(const ushort_t* p, float s) {
    uint4 r = *(const uint4*)p;
    unsigned aa[4] = {r.x, r.y, r.z, r.w};
    short8 o;
#pragma unroll
    for (int i = 0; i < 4; ++i) {
        o[2 * i]     = (short)f2bf(bf2f((ushort_t)(aa[i] & 0xffffu)) * s);
        o[2 * i + 1] = (short)f2bf(bf2f((ushort_t)(aa[i] >> 16)) * s);
    }
    return o;
}

// ---------------- K0: dtype detector ----------------
__global__ __launch_bounds__(64) void detect_kernel(const ushort_t* __restrict__ x,
                                                    int* __restrict__ flag)
{
    int lane = threadIdx.x;
    int cnt = 0;
#pragma unroll
    for (int i = 0; i < 4; ++i) {
        ushort_t u = x[lane * 4 + i];
        int e = (u >> 7) & 0xFF;
        if (e >= 80 && e <= 141) cnt++;
    }
#pragma unroll
    for (int d = 1; d < 64; d <<= 1) cnt += __shfl_xor(cnt, d, 64);
    if (lane == 0) *flag = (cnt >= 224) ? 1 : 0;   // 1 = inputs are bf16
}

// ---------------- K0.5: stage all inputs as bf16 ----------------
struct Ptrs13 { const void* p[13]; };

__global__ __launch_bounds__(256) void convert_kernel(Ptrs13 ptrs,
                                                      const int* __restrict__ flag,
                                                      ushort_t* __restrict__ dst)
{
    const int offs[14] = {OFF_X, OFF_FCW, OFF_FCB, OFF_WIH, OFF_WHH, OFF_BIH,
                          OFF_BHH, OFF_OFW, OFF_OFB, OFF_FINW, OFF_FINB,
                          OFF_FOW, OFF_FOB, CONV_TOTAL};
    const bool isbf = (*flag != 0);
    for (int idx = blockIdx.x * 256 + threadIdx.x; idx < CONV_TOTAL;
         idx += gridDim.x * 256) {
        int s = 0;
#pragma unroll
        for (int j = 1; j < 13; ++j) if (idx >= offs[j]) s = j;
        int k = idx - offs[s];
        ushort_t v = isbf ? ((const ushort_t*)ptrs.p[s])[k]
                          : f2bf(((const float*)ptrs.p[s])[k]);
        dst[idx] = v;
    }
}

// ---------------- K1: fused 4-layer GRU + out-FC + sigmoid ----------------
// Orientation: A=weights (m=gate-col), B=activations (n=seq).
// D[col][seq]: lane holds seq = lane&15, cols = jb + 4*quad + i.
__global__ __launch_bounds__(256) void gru_kernel(
    const ushort_t* __restrict__ x, const ushort_t* __restrict__ fcw,
    const ushort_t* __restrict__ fcb, const ushort_t* __restrict__ wih,
    const ushort_t* __restrict__ whh, const ushort_t* __restrict__ bih,
    const ushort_t* __restrict__ bhh, const ushort_t* __restrict__ ofw,
    const ushort_t* __restrict__ ofb, float* __restrict__ Aslow,
    float* __restrict__ gslow)
{
    __shared__ short8 Xs8[4096];   // 64 KB: 16 seq x 32 t x 64 feat, swizzled
    short* Xs = (short*)Xs8;
    const int tid = threadIdx.x;
    const int w = tid >> 6, lane = tid & 63;
    const int q = lane >> 4, m = lane & 15;
    const int jb = w * 16;
    const int n0 = blockIdx.x * 16;

    // ---- fill layer-0 input: relu(x_s * fc_in_w + fc_in_b) ----
#pragma unroll 1
    for (int ii = 0; ii < 16; ++ii) {
        int cid = ii * 256 + tid;
        int seq = cid & 15, kb = (cid >> 4) & 7, t = cid >> 7;
        int n = n0 + seq; if (n > NSEQ - 1) n = NSEQ - 1;
        int b = n / NSLOW, s = n - b * NSLOW;
        float xv = bf2f(x[b * T_LEN + s * 16 + t]);
        short8 v;
#pragma unroll
        for (int i = 0; i < 8; ++i) {
            int g = kb * 8 + i;
            float h = fmaf(xv, bf2f(fcw[g]), bf2f(fcb[g]));
            h = h > 0.f ? h : 0.f;
            v[i] = (short)f2bf(h);
        }
        Xs8[xoff(t, kb, seq) >> 3] = v;
    }

    const int col0 = jb + 4 * q;            // this lane's 4 gate-cols
    const int kbw = (col0 >> 3);            // write feature-block
    const int wsub = (col0 & 7);            // 0 or 4
    const int kofs = q * 8;
    // write base (t=0), short index; step +1024 shorts per t
    const int wbase0 = ((kbw << 4) + (m ^ (kbw & 7))) * 8 + wsub;

    float hc[4];
#pragma unroll 1
    for (int l = 0; l < NL; ++l) {
        const ushort_t* wl = wih + l * G3 * GH;
        const ushort_t* ul = whh + l * G3 * GH;
        // A-frags (weights): lane m = gate-col jb+m, k contiguous
        short8 wR0 = load_frag_scaled(wl + (0 * 64 + jb + m) * 64 + kofs, -L2E);
        short8 wR1 = load_frag_scaled(wl + (0 * 64 + jb + m) * 64 + 32 + kofs, -L2E);
        short8 wZ0 = load_frag_scaled(wl + (1 * 64 + jb + m) * 64 + kofs, -L2E);
        short8 wZ1 = load_frag_scaled(wl + (1 * 64 + jb + m) * 64 + 32 + kofs, -L2E);
        short8 wN0 = load_frag_scaled(wl + (2 * 64 + jb + m) * 64 + kofs, 2.f * L2E);
        short8 wN1 = load_frag_scaled(wl + (2 * 64 + jb + m) * 64 + 32 + kofs, 2.f * L2E);
        short8 uR0 = load_frag_scaled(ul + (0 * 64 + jb + m) * 64 + kofs, -L2E);
        short8 uR1 = load_frag_scaled(ul + (0 * 64 + jb + m) * 64 + 32 + kofs, -L2E);
        short8 uZ0 = load_frag_scaled(ul + (1 * 64 + jb + m) * 64 + kofs, -L2E);
        short8 uZ1 = load_frag_scaled(ul + (1 * 64 + jb + m) * 64 + 32 + kofs, -L2E);
        short8 uN0 = load_frag_scaled(ul + (2 * 64 + jb + m) * 64 + kofs, 2.f * L2E);
        short8 uN1 = load_frag_scaled(ul + (2 * 64 + jb + m) * 64 + 32 + kofs, 2.f * L2E);

        float bR[4], bZ[4], bNX[4], bNH[4];
#pragma unroll
        for (int i = 0; i < 4; ++i) {
            int c = col0 + i;
            bR[i]  = -L2E * (bf2f(bih[l * G3 + c]) + bf2f(bhh[l * G3 + c]));
            bZ[i]  = -L2E * (bf2f(bih[l * G3 + 64 + c]) + bf2f(bhh[l * G3 + 64 + c]));
            bNX[i] = 2.f * L2E * bf2f(bih[l * G3 + 128 + c]);
            bNH[i] = 2.f * L2E * bf2f(bhh[l * G3 + 128 + c]);
        }

        hc[0] = hc[1] = hc[2] = hc[3] = 0.f;

        __syncthreads();                    // prev layer's writes visible
        int iA = xoff(0, q, m) >> 3;        // x-chain, kb=q     (+128/t)
        int iB = xoff(0, 4 + q, m) >> 3;    // x-chain, kb=4+q
        short8 bx0 = Xs8[iA];
        short8 bx1 = Xs8[iB];
        int wb = wbase0;

#pragma unroll 1
        for (int t = 0; t < 32; ++t) {
            __syncthreads();                // step t-1 h-writes visible
            short8 bh0 = bx0, bh1 = bx1;
            if (t > 0) {                    // h(t-1) from slot t-1
                bh0 = Xs8[iA - 128];
                bh1 = Xs8[iB - 128];
            }
            short8 nx0 = bx0, nx1 = bx1;
            if (t < 31) {                   // prefetch X(t+1), slot t+1
                nx0 = Xs8[iA + 128];
                nx1 = Xs8[iB + 128];
            }
            f32x4 aR  = {bR[0], bR[1], bR[2], bR[3]};
            f32x4 aZ  = {bZ[0], bZ[1], bZ[2], bZ[3]};
            f32x4 aNX = {bNX[0], bNX[1], bNX[2], bNX[3]};
            f32x4 aNH = {bNH[0], bNH[1], bNH[2], bNH[3]};
            aR  = mfma16(wR0, bx0, aR);  aR  = mfma16(wR1, bx1, aR);
            aZ  = mfma16(wZ0, bx0, aZ);  aZ  = mfma16(wZ1, bx1, aZ);
            aNX = mfma16(wN0, bx0, aNX); aNX = mfma16(wN1, bx1, aNX);
            if (t > 0) {
                aR  = mfma16(uR0, bh0, aR);  aR  = mfma16(uR1, bh1, aR);
                aZ  = mfma16(uZ0, bh0, aZ);  aZ  = mfma16(uZ1, bh1, aZ);
                aNH = mfma16(uN0, bh0, aNH); aNH = mfma16(uN1, bh1, aNH);
            }
#pragma unroll
            for (int i = 0; i < 4; ++i) {
                float r = __builtin_amdgcn_rcpf(1.f + __builtin_amdgcn_exp2f(aR[i]));
                float z = __builtin_amdgcn_rcpf(1.f + __builtin_amdgcn_exp2f(aZ[i]));
                float yp = fmaf(r, aNH[i], aNX[i]);
                float nn = fmaf(-2.f,
                    __builtin_amdgcn_rcpf(1.f + __builtin_amdgcn_exp2f(yp)), 1.f);
                hc[i] = fmaf(z, hc[i] - nn, nn);
            }
            unsigned lo = pk2bf(hc[0], hc[1]);
            unsigned hi = pk2bf(hc[2], hc[3]);
            *(uint2*)(Xs + wb) = make_uint2(lo, hi);   // ds_write_b64, slot t
            bx0 = nx0; bx1 = nx1;
            iA += 128; iB += 128; wb += 1024;
        }
    }

    // ---- epilogue: eps = h_last @ out_fc_w^T + b ----
    __syncthreads();
    short8 aL0 = Xs8[xoff(31, q, m) >> 3];
    short8 aL1 = Xs8[xoff(31, 4 + q, m) >> 3];
    float sc = (w < 2) ? -L2E : 1.f;
    short8 o0 = load_frag_scaled(ofw + (jb + m) * 64 + kofs, sc);
    short8 o1 = load_frag_scaled(ofw + (jb + m) * 64 + 32 + kofs, sc);
    f32x4 aE = {bf2f(ofb[col0]) * sc, bf2f(ofb[col0 + 1]) * sc,
                bf2f(ofb[col0 + 2]) * sc, bf2f(ofb[col0 + 3]) * sc};
    aE = mfma16(o0, aL0, aE);
    aE = mfma16(o1, aL1, aE);
    int n = n0 + m;           // pad rows (>=NSEQ) land in rows < 8192: harmless
    if (w < 2) {
        f32x4 v;
#pragma unroll
        for (int i = 0; i < 4; ++i)
            v[i] = __builtin_amdgcn_rcpf(1.f + __builtin_amdgcn_exp2f(aE[i]));
        *(f32x4*)(Aslow + n * HID + col0) = v;
    } else {
        *(f32x4*)(gslow + n * HID + (col0 - 32)) = aE;
    }
}

// ---------------- K2: per-chunk (prod A, partial sum), 256 chunks ----------
__global__ __launch_bounds__(256) void pass1_kernel(
    const ushort_t* __restrict__ x, const float* __restrict__ Aslow,
    const float* __restrict__ gslow, const ushort_t* __restrict__ finw,
    const ushort_t* __restrict__ finb, float* __restrict__ P,
    float* __restrict__ S)
{
    int gt = blockIdx.x * 256 + threadIdx.x;    // 32768 = 4b * 256c * 32h
    int h = gt & 31, c = (gt >> 5) & 255, b = gt >> 13;
    float fw = bf2f(finw[h]), fb = bf2f(finb[h]);
    float Pv = 1.f, Sv = 0.f;
    int t0 = c * 128;
#pragma unroll 1
    for (int seg = 0; seg < 8; ++seg) {
        int sidx = (t0 >> 4) + seg - 1;
        if (sidx < 0) sidx = 0;
        if (sidx > NSLOW - 1) sidx = NSLOW - 1;
        float A = Aslow[(b * NSLOW + sidx) * HID + h];
        float g = gslow[(b * NSLOW + sidx) * HID + h];
        float fwg = fw * g, fbg = fb * g;
        const uint4* px = (const uint4*)(x + b * T_LEN + t0 + seg * 16);
        uint4 ra = px[0], rb = px[1];
        unsigned xa[8] = {ra.x, ra.y, ra.z, ra.w, rb.x, rb.y, rb.z, rb.w};
#pragma unroll
        for (int j = 0; j < 8; ++j) {
            float x0 = bf2f((ushort_t)(xa[j] & 0xffffu));
            float x1 = bf2f((ushort_t)(xa[j] >> 16));
            Sv = fmaf(A, Sv, fmaf(x0, fwg, fbg));
            Sv = fmaf(A, Sv, fmaf(x1, fwg, fbg));
        }
        float A2 = A * A, A4 = A2 * A2, A8 = A4 * A4;
        Pv *= A8 * A8;
    }
    P[(b * HID + h) * NCH + c] = Pv;
    S[(b * HID + h) * NCH + c] = Sv;
}

// ---------------- K3: scan of chunk summaries ----------------
__global__ __launch_bounds__(128) void scan_kernel(
    const float* __restrict__ P, const float* __restrict__ S,
    float* __restrict__ Hpre)
{
    int tid = threadIdx.x;   // 128 = (b,h)
    const float4* p4 = (const float4*)(P + tid * NCH);
    const float4* s4 = (const float4*)(S + tid * NCH);
    float* hp = Hpre + tid * NCH;
    float hr = 0.f;
#pragma unroll 1
    for (int c = 0; c < NCH / 4; ++c) {
        float4 pv = p4[c], sv = s4[c];
        hp[4 * c + 0] = hr; hr = fmaf(pv.x, hr, sv.x);
        hp[4 * c + 1] = hr; hr = fmaf(pv.y, hr, sv.y);
        hp[4 * c + 2] = hr; hr = fmaf(pv.z, hr, sv.z);
        hp[4 * c + 3] = hr; hr = fmaf(pv.w, hr, sv.w);
    }
}

// ---------------- K4: recompute states + fused output dot ----------------
__global__ __launch_bounds__(256) void pass2_kernel(
    const ushort_t* __restrict__ x, const float* __restrict__ Aslow,
    const float* __restrict__ gslow, const float* __restrict__ Hpre,
    const ushort_t* __restrict__ finw, const ushort_t* __restrict__ finb,
    const ushort_t* __restrict__ fow, const ushort_t* __restrict__ fob,
    const int* __restrict__ flag, void* __restrict__ outv)
{
    int wv = blockIdx.x * 4 + (threadIdx.x >> 6);   // 0..511
    int lane = threadIdx.x & 63;
    int half = lane >> 5, h = lane & 31;
    int pair = wv * 2 + half;                       // 0..1023 = b*NCH + c
    int b = pair >> 8, c = pair & 255;
    const bool isbf = (*flag != 0);
    ushort_t* outb = (ushort_t*)outv;
    float* outf = (float*)outv;
    float hv = Hpre[(b * HID + h) * NCH + c];
    float fw = bf2f(finw[h]), fb = bf2f(finb[h]);
    float wo = bf2f(fow[h]), ob = bf2f(fob[0]);
    int t0 = c * 128;
#pragma unroll 1
    for (int blk = 0; blk < 4; ++blk) {
        float ykeep = 0.f;
        float A = 0.f, fwg = 0.f, fbg = 0.f;
#pragma unroll
        for (int tt = 0; tt < 32; ++tt) {
            int t = t0 + blk * 32 + tt;
            if ((tt & 15) == 0) {
                int sidx = (t >> 4) - 1;
                if (sidx < 0) sidx = 0;
                A = Aslow[(b * NSLOW + sidx) * HID + h];
                float g = gslow[(b * NSLOW + sidx) * HID + h];
                fwg = fw * g; fbg = fb * g;
            }
            float xv = bf2f(x[b * T_LEN + t]);
            hv = fmaf(A, hv, fmaf(xv, fwg, fbg));
            float y = hv * wo;
            y += __shfl_xor(y, 1, 64);
            y += __shfl_xor(y, 2, 64);
            y += __shfl_xor(y, 4, 64);
            y += __shfl_xor(y, 8, 64);
            y += __shfl_xor(y, 16, 64);
            if (tt == h) ykeep = y + ob;
        }
        int oidx = b * T_LEN + t0 + blk * 32 + h;
        if (isbf) outb[oidx] = f2bf(ykeep);
        else      outf[oidx] = ykeep;
    }
}

extern "C" void kernel_launch(void* const* d_in, const int* in_sizes, int n_in,
                              void* d_out, int out_size, void* d_ws, size_t ws_size,
                              hipStream_t stream)
{
    ushort_t* cv = (ushort_t*)d_ws;
    const ushort_t* x    = cv + OFF_X;
    const ushort_t* fcw  = cv + OFF_FCW;
    const ushort_t* fcb  = cv + OFF_FCB;
    const ushort_t* wih  = cv + OFF_WIH;
    const ushort_t* whh  = cv + OFF_WHH;
    const ushort_t* bih  = cv + OFF_BIH;
    const ushort_t* bhh  = cv + OFF_BHH;
    const ushort_t* ofw  = cv + OFF_OFW;
    const ushort_t* ofb  = cv + OFF_OFB;
    const ushort_t* finw = cv + OFF_FINW;
    const ushort_t* finb = cv + OFF_FINB;
    const ushort_t* fow  = cv + OFF_FOW;
    const ushort_t* fob  = cv + OFF_FOB;

    float* Aslow = (float*)((char*)d_ws + CONV_PAD_BYTES);  // 8192*32 f32
    float* gslow = Aslow + 8192 * 32;
    float* P     = gslow + 8192 * 32;          // 4*32*NCH
    float* S     = P + 4 * 32 * NCH;
    float* Hpre  = S + 4 * 32 * NCH;
    int*   flag  = (int*)(Hpre + 4 * 32 * NCH);

    Ptrs13 ptrs;
    for (int i = 0; i < 13; ++i) ptrs.p[i] = d_in[i];

    detect_kernel<<<dim3(1), dim3(64), 0, stream>>>((const ushort_t*)d_in[0], flag);
    convert_kernel<<<dim3(920), dim3(256), 0, stream>>>(ptrs, flag, cv);
    gru_kernel<<<dim3(512), dim3(256), 0, stream>>>(
        x, fcw, fcb, wih, whh, bih, bhh, ofw, ofb, Aslow, gslow);
    pass1_kernel<<<dim3(128), dim3(256), 0, stream>>>(
        x, Aslow, gslow, finw, finb, P, S);
    scan_kernel<<<dim3(1), dim3(128), 0, stream>>>(P, S, Hpre);
    pass2_kernel<<<dim3(128), dim3(256), 0, stream>>>(
        x, Aslow, gslow, Hpre, finw, finb, fow, fob, flag, d_out);
}

// Round 5
// 191.431 us; speedup vs baseline: 1.1167x; 1.1065x over previous
//
#include <hip/hip_runtime.h>
#include <hip/hip_bf16.h>

typedef __bf16 bf16x8 __attribute__((ext_vector_type(8)));
typedef short short8 __attribute__((ext_vector_type(8)));
typedef float f32x4 __attribute__((ext_vector_type(4)));
typedef unsigned short ushort_t;

#define T_LEN 32768
#define B_SZ 4
#define NSLOW 2047
#define NSEQ (B_SZ * NSLOW)   // 8188
#define GH 64
#define G3 192
#define NL 4
#define HID 32
#define NCH 256               // fast-path chunks per batch (len 128)
#define L2E 1.44269504088896341f

// staging-buffer (bf16) element offsets, concatenated in input order
#define OFF_X    0
#define OFF_FCW  131072
#define OFF_FCB  131136
#define OFF_WIH  131200
#define OFF_WHH  180352
#define OFF_BIH  229504
#define OFF_BHH  230272
#define OFF_OFW  231040
#define OFF_OFB  235136
#define OFF_FINW 235200
#define OFF_FINB 235232
#define OFF_FOW  235264
#define OFF_FOB  235296
#define CONV_TOTAL 235297
#define CONV_PAD_BYTES 470656   // 16B-aligned end of staging region

static __device__ __forceinline__ float bf2f(ushort_t u) {
    union { unsigned u; float f; } c; c.u = ((unsigned)u) << 16; return c.f;
}
static __device__ __forceinline__ ushort_t f2bf(float f) {
    union { float f; unsigned u; } c; c.f = f;
    unsigned r = (c.u + 0x7FFFu + ((c.u >> 16) & 1u)) >> 16;
    return (ushort_t)r;
}
static __device__ __forceinline__ unsigned pk2bf(float a, float b) {
    float2 f; f.x = a; f.y = b;
    __hip_bfloat162 h = __float22bfloat162_rn(f);   // v_cvt_pk_bf16_f32
    unsigned u;
    __builtin_memcpy(&u, &h, 4);
    return u;
}
static __device__ __forceinline__ f32x4 mfma16(short8 a, short8 b, f32x4 c) {
    return __builtin_amdgcn_mfma_f32_16x16x32_bf16(
        __builtin_bit_cast(bf16x8, a), __builtin_bit_cast(bf16x8, b), c, 0, 0, 0);
}
// LDS layout: short off = ((t*8 + kb)*16 + (seq ^ (kb&7)))*8 + i
static __device__ __forceinline__ int xoff(int t, int kb, int seq) {
    return ((((t << 3) + kb) << 4) + (seq ^ (kb & 7))) << 3;
}
static __device__ __forceinline__ short8 load_frag_scaled(const ushort_t* p, float s) {
    uint4 r = *(const uint4*)p;
    unsigned aa[4] = {r.x, r.y, r.z, r.w};
    short8 o;
#pragma unroll
    for (int i = 0; i < 4; ++i) {
        o[2 * i]     = (short)f2bf(bf2f((ushort_t)(aa[i] & 0xffffu)) * s);
        o[2 * i + 1] = (short)f2bf(bf2f((ushort_t)(aa[i] >> 16)) * s);
    }
    return o;
}

// ---------------- K0: stage all inputs as bf16 (self-detecting dtype) ------
struct Ptrs13 { const void* p[13]; };

__global__ __launch_bounds__(256) void convert_kernel(Ptrs13 ptrs,
                                                      int* __restrict__ flag,
                                                      ushort_t* __restrict__ dst)
{
    // per-block dtype detection on the first 256 ushorts of x
    __shared__ int scnt;
    if (threadIdx.x == 0) scnt = 0;
    __syncthreads();
    {
        ushort_t u = ((const ushort_t*)ptrs.p[0])[threadIdx.x];
        int e = (u >> 7) & 0xFF;
        int ok = (e >= 80 && e <= 141) ? 1 : 0;
#pragma unroll
        for (int d = 1; d < 64; d <<= 1) ok += __shfl_xor(ok, d, 64);
        if ((threadIdx.x & 63) == 0) atomicAdd(&scnt, ok);
    }
    __syncthreads();
    const bool isbf = (scnt >= 224);   // bf16 data: ~256/256 sane exponents
    if (blockIdx.x == 0 && threadIdx.x == 0) *flag = isbf ? 1 : 0;

    const int offs[14] = {OFF_X, OFF_FCW, OFF_FCB, OFF_WIH, OFF_WHH, OFF_BIH,
                          OFF_BHH, OFF_OFW, OFF_OFB, OFF_FINW, OFF_FINB,
                          OFF_FOW, OFF_FOB, CONV_TOTAL};
    for (int idx = blockIdx.x * 256 + threadIdx.x; idx < CONV_TOTAL;
         idx += gridDim.x * 256) {
        int s = 0;
#pragma unroll
        for (int j = 1; j < 13; ++j) if (idx >= offs[j]) s = j;
        int k = idx - offs[s];
        ushort_t v = isbf ? ((const ushort_t*)ptrs.p[s])[k]
                          : f2bf(((const float*)ptrs.p[s])[k]);
        dst[idx] = v;
    }
}

// ---------------- K1: fused 4-layer GRU + out-FC + sigmoid ----------------
// Orientation: A=weights (m=gate-col), B=activations (n=seq).
// D[col][seq]: lane holds seq = lane&15, cols = jb + 4*quad + i.
// K-loop: xacc(t+1)=bias+Wih*X(t+1) computed at end of step t (barrier
// shadow); post-barrier chain is only 2 MFMAs (Whh*h) + gates.
__global__ __launch_bounds__(256, 2) void gru_kernel(
    const ushort_t* __restrict__ x, const ushort_t* __restrict__ fcw,
    const ushort_t* __restrict__ fcb, const ushort_t* __restrict__ wih,
    const ushort_t* __restrict__ whh, const ushort_t* __restrict__ bih,
    const ushort_t* __restrict__ bhh, const ushort_t* __restrict__ ofw,
    const ushort_t* __restrict__ ofb, float* __restrict__ Aslow,
    float* __restrict__ gslow)
{
    __shared__ short8 Xs8[4096];   // 64 KB: 16 seq x 32 t x 64 feat, swizzled
    short* Xs = (short*)Xs8;
    const int tid = threadIdx.x;
    const int w = tid >> 6, lane = tid & 63;
    const int q = lane >> 4, m = lane & 15;
    const int jb = w * 16;
    const int n0 = blockIdx.x * 16;

    // ---- fill layer-0 input: relu(x_s * fc_in_w + fc_in_b) ----
#pragma unroll 1
    for (int ii = 0; ii < 16; ++ii) {
        int cid = ii * 256 + tid;
        int seq = cid & 15, kb = (cid >> 4) & 7, t = cid >> 7;
        int n = n0 + seq; if (n > NSEQ - 1) n = NSEQ - 1;
        int b = n / NSLOW, s = n - b * NSLOW;
        float xv = bf2f(x[b * T_LEN + s * 16 + t]);
        short8 v;
#pragma unroll
        for (int i = 0; i < 8; ++i) {
            int g = kb * 8 + i;
            float h = fmaf(xv, bf2f(fcw[g]), bf2f(fcb[g]));
            h = h > 0.f ? h : 0.f;
            v[i] = (short)f2bf(h);
        }
        Xs8[xoff(t, kb, seq) >> 3] = v;
    }

    const int col0 = jb + 4 * q;            // this lane's 4 gate-cols
    const int kbw = (col0 >> 3);            // write feature-block
    const int wsub = (col0 & 7);            // 0 or 4
    const int kofs = q * 8;
    const int wbase0 = ((kbw << 4) + (m ^ (kbw & 7))) * 8 + wsub;

    float hc[4];
#pragma unroll 1
    for (int l = 0; l < NL; ++l) {
        const ushort_t* wl = wih + l * G3 * GH;
        const ushort_t* ul = whh + l * G3 * GH;
        // A-frags (weights): lane m = gate-col jb+m, k contiguous
        short8 wR0 = load_frag_scaled(wl + (0 * 64 + jb + m) * 64 + kofs, -L2E);
        short8 wR1 = load_frag_scaled(wl + (0 * 64 + jb + m) * 64 + 32 + kofs, -L2E);
        short8 wZ0 = load_frag_scaled(wl + (1 * 64 + jb + m) * 64 + kofs, -L2E);
        short8 wZ1 = load_frag_scaled(wl + (1 * 64 + jb + m) * 64 + 32 + kofs, -L2E);
        short8 wN0 = load_frag_scaled(wl + (2 * 64 + jb + m) * 64 + kofs, 2.f * L2E);
        short8 wN1 = load_frag_scaled(wl + (2 * 64 + jb + m) * 64 + 32 + kofs, 2.f * L2E);
        short8 uR0 = load_frag_scaled(ul + (0 * 64 + jb + m) * 64 + kofs, -L2E);
        short8 uR1 = load_frag_scaled(ul + (0 * 64 + jb + m) * 64 + 32 + kofs, -L2E);
        short8 uZ0 = load_frag_scaled(ul + (1 * 64 + jb + m) * 64 + kofs, -L2E);
        short8 uZ1 = load_frag_scaled(ul + (1 * 64 + jb + m) * 64 + 32 + kofs, -L2E);
        short8 uN0 = load_frag_scaled(ul + (2 * 64 + jb + m) * 64 + kofs, 2.f * L2E);
        short8 uN1 = load_frag_scaled(ul + (2 * 64 + jb + m) * 64 + 32 + kofs, 2.f * L2E);

        f32x4 bRv, bZv, bNXv, bNHv;
#pragma unroll
        for (int i = 0; i < 4; ++i) {
            int c = col0 + i;
            bRv[i]  = -L2E * (bf2f(bih[l * G3 + c]) + bf2f(bhh[l * G3 + c]));
            bZv[i]  = -L2E * (bf2f(bih[l * G3 + 64 + c]) + bf2f(bhh[l * G3 + 64 + c]));
            bNXv[i] = 2.f * L2E * bf2f(bih[l * G3 + 128 + c]);
            bNHv[i] = 2.f * L2E * bf2f(bhh[l * G3 + 128 + c]);
        }

        hc[0] = hc[1] = hc[2] = hc[3] = 0.f;

        __syncthreads();                    // layer input fully written
        int iA = xoff(0, q, m) >> 3;        // kb=q chain (+128/t)
        int iB = xoff(0, 4 + q, m) >> 3;    // kb=4+q chain
        int wb = wbase0;

        // ---- t = 0 peeled: h=0, gates from xacc only ----
        short8 cx0 = Xs8[iA], cx1 = Xs8[iB];          // X(0)
        short8 nx0 = Xs8[iA + 128], nx1 = Xs8[iB + 128]; // X(1)
        f32x4 xR = bRv, xZ = bZv, xN = bNXv;
        xR = mfma16(wR0, cx0, xR); xR = mfma16(wR1, cx1, xR);
        xZ = mfma16(wZ0, cx0, xZ); xZ = mfma16(wZ1, cx1, xZ);
        xN = mfma16(wN0, cx0, xN); xN = mfma16(wN1, cx1, xN);
#pragma unroll
        for (int i = 0; i < 4; ++i) {
            float r = __builtin_amdgcn_rcpf(1.f + __builtin_amdgcn_exp2f(xR[i]));
            float z = __builtin_amdgcn_rcpf(1.f + __builtin_amdgcn_exp2f(xZ[i]));
            float yp = fmaf(r, bNHv[i], xN[i]);
            float nn = fmaf(-2.f,
                __builtin_amdgcn_rcpf(1.f + __builtin_amdgcn_exp2f(yp)), 1.f);
            hc[i] = fmaf(z, hc[i] - nn, nn);
        }
        *(uint2*)(Xs + wb) = make_uint2(pk2bf(hc[0], hc[1]), pk2bf(hc[2], hc[3]));
        // xacc(1) in barrier shadow
        xR = bRv; xZ = bZv; xN = bNXv;
        xR = mfma16(wR0, nx0, xR); xR = mfma16(wR1, nx1, xR);
        xZ = mfma16(wZ0, nx0, xZ); xZ = mfma16(wZ1, nx1, xZ);
        xN = mfma16(wN0, nx0, xN); xN = mfma16(wN1, nx1, xN);
        iA += 128; iB += 128; wb += 1024;

#pragma unroll 1
        for (int t = 1; t < 32; ++t) {
            __syncthreads();                // h(t-1) visible
            short8 bh0 = Xs8[iA - 128];     // h(t-1), slot t-1
            short8 bh1 = Xs8[iB - 128];
            short8 px0, px1;
            if (t < 31) {                   // X(t+1), slot t+1 (untouched)
                px0 = Xs8[iA + 128];
                px1 = Xs8[iB + 128];
            }
            f32x4 aR = xR, aZ = xZ, aNH = bNHv;
            aR  = mfma16(uR0, bh0, aR);  aR  = mfma16(uR1, bh1, aR);
            aZ  = mfma16(uZ0, bh0, aZ);  aZ  = mfma16(uZ1, bh1, aZ);
            aNH = mfma16(uN0, bh0, aNH); aNH = mfma16(uN1, bh1, aNH);
#pragma unroll
            for (int i = 0; i < 4; ++i) {
                float r = __builtin_amdgcn_rcpf(1.f + __builtin_amdgcn_exp2f(aR[i]));
                float z = __builtin_amdgcn_rcpf(1.f + __builtin_amdgcn_exp2f(aZ[i]));
                float yp = fmaf(r, aNH[i], xN[i]);
                float nn = fmaf(-2.f,
                    __builtin_amdgcn_rcpf(1.f + __builtin_amdgcn_exp2f(yp)), 1.f);
                hc[i] = fmaf(z, hc[i] - nn, nn);
            }
            *(uint2*)(Xs + wb) =
                make_uint2(pk2bf(hc[0], hc[1]), pk2bf(hc[2], hc[3]));
            if (t < 31) {                   // xacc(t+1), barrier shadow
                xR = bRv; xZ = bZv; xN = bNXv;
                xR = mfma16(wR0, px0, xR); xR = mfma16(wR1, px1, xR);
                xZ = mfma16(wZ0, px0, xZ); xZ = mfma16(wZ1, px1, xZ);
                xN = mfma16(wN0, px0, xN); xN = mfma16(wN1, px1, xN);
            }
            iA += 128; iB += 128; wb += 1024;
        }
    }

    // ---- epilogue: eps = h_last @ out_fc_w^T + b ----
    __syncthreads();
    short8 aL0 = Xs8[xoff(31, q, m) >> 3];
    short8 aL1 = Xs8[xoff(31, 4 + q, m) >> 3];
    float sc = (w < 2) ? -L2E : 1.f;
    short8 o0 = load_frag_scaled(ofw + (jb + m) * 64 + kofs, sc);
    short8 o1 = load_frag_scaled(ofw + (jb + m) * 64 + 32 + kofs, sc);
    f32x4 aE = {bf2f(ofb[col0]) * sc, bf2f(ofb[col0 + 1]) * sc,
                bf2f(ofb[col0 + 2]) * sc, bf2f(ofb[col0 + 3]) * sc};
    aE = mfma16(o0, aL0, aE);
    aE = mfma16(o1, aL1, aE);
    int n = n0 + m;           // pad rows land in rows < 8192: harmless
    if (w < 2) {
        f32x4 v;
#pragma unroll
        for (int i = 0; i < 4; ++i)
            v[i] = __builtin_amdgcn_rcpf(1.f + __builtin_amdgcn_exp2f(aE[i]));
        *(f32x4*)(Aslow + n * HID + col0) = v;
    } else {
        *(f32x4*)(gslow + n * HID + (col0 - 32)) = aE;
    }
}

// ---------------- K2: per-chunk (prod A, partial sum), 256 chunks ----------
__global__ __launch_bounds__(256) void pass1_kernel(
    const ushort_t* __restrict__ x, const float* __restrict__ Aslow,
    const float* __restrict__ gslow, const ushort_t* __restrict__ finw,
    const ushort_t* __restrict__ finb, float* __restrict__ P,
    float* __restrict__ S)
{
    int gt = blockIdx.x * 256 + threadIdx.x;    // 32768 = 4b * 256c * 32h
    int h = gt & 31, c = (gt >> 5) & 255, b = gt >> 13;
    float fw = bf2f(finw[h]), fb = bf2f(finb[h]);
    float Pv = 1.f, Sv = 0.f;
    int t0 = c * 128;
#pragma unroll 1
    for (int seg = 0; seg < 8; ++seg) {
        int sidx = (t0 >> 4) + seg - 1;
        if (sidx < 0) sidx = 0;
        if (sidx > NSLOW - 1) sidx = NSLOW - 1;
        float A = Aslow[(b * NSLOW + sidx) * HID + h];
        float g = gslow[(b * NSLOW + sidx) * HID + h];
        float fwg = fw * g, fbg = fb * g;
        const uint4* px = (const uint4*)(x + b * T_LEN + t0 + seg * 16);
        uint4 ra = px[0], rb = px[1];
        unsigned xa[8] = {ra.x, ra.y, ra.z, ra.w, rb.x, rb.y, rb.z, rb.w};
#pragma unroll
        for (int j = 0; j < 8; ++j) {
            float x0 = bf2f((ushort_t)(xa[j] & 0xffffu));
            float x1 = bf2f((ushort_t)(xa[j] >> 16));
            Sv = fmaf(A, Sv, fmaf(x0, fwg, fbg));
            Sv = fmaf(A, Sv, fmaf(x1, fwg, fbg));
        }
        float A2 = A * A, A4 = A2 * A2, A8 = A4 * A4;
        Pv *= A8 * A8;
    }
    P[(b * HID + h) * NCH + c] = Pv;
    S[(b * HID + h) * NCH + c] = Sv;
}

// ---------------- K3: scan of chunk summaries ----------------
__global__ __launch_bounds__(128) void scan_kernel(
    const float* __restrict__ P, const float* __restrict__ S,
    float* __restrict__ Hpre)
{
    int tid = threadIdx.x;   // 128 = (b,h)
    const float4* p4 = (const float4*)(P + tid * NCH);
    const float4* s4 = (const float4*)(S + tid * NCH);
    float* hp = Hpre + tid * NCH;
    float hr = 0.f;
#pragma unroll 8
    for (int c = 0; c < NCH / 4; ++c) {
        float4 pv = p4[c], sv = s4[c];
        hp[4 * c + 0] = hr; hr = fmaf(pv.x, hr, sv.x);
        hp[4 * c + 1] = hr; hr = fmaf(pv.y, hr, sv.y);
        hp[4 * c + 2] = hr; hr = fmaf(pv.z, hr, sv.z);
        hp[4 * c + 3] = hr; hr = fmaf(pv.w, hr, sv.w);
    }
}

// ---------------- K4: recompute states + fused output dot ----------------
__global__ __launch_bounds__(256) void pass2_kernel(
    const ushort_t* __restrict__ x, const float* __restrict__ Aslow,
    const float* __restrict__ gslow, const float* __restrict__ Hpre,
    const ushort_t* __restrict__ finw, const ushort_t* __restrict__ finb,
    const ushort_t* __restrict__ fow, const ushort_t* __restrict__ fob,
    const int* __restrict__ flag, void* __restrict__ outv)
{
    int wv = blockIdx.x * 4 + (threadIdx.x >> 6);   // 0..511
    int lane = threadIdx.x & 63;
    int half = lane >> 5, h = lane & 31;
    int pair = wv * 2 + half;                       // 0..1023 = b*NCH + c
    int b = pair >> 8, c = pair & 255;
    const bool isbf = (*flag != 0);
    ushort_t* outb = (ushort_t*)outv;
    float* outf = (float*)outv;
    float hv = Hpre[(b * HID + h) * NCH + c];
    float fw = bf2f(finw[h]), fb = bf2f(finb[h]);
    float wo = bf2f(fow[h]), ob = bf2f(fob[0]);
    int t0 = c * 128;
#pragma unroll 1
    for (int blk = 0; blk < 4; ++blk) {
        float ykeep = 0.f;
        float A = 0.f, fwg = 0.f, fbg = 0.f;
#pragma unroll
        for (int tt = 0; tt < 32; ++tt) {
            int t = t0 + blk * 32 + tt;
            if ((tt & 15) == 0) {
                int sidx = (t >> 4) - 1;
                if (sidx < 0) sidx = 0;
                A = Aslow[(b * NSLOW + sidx) * HID + h];
                float g = gslow[(b * NSLOW + sidx) * HID + h];
                fwg = fw * g; fbg = fb * g;
            }
            float xv = bf2f(x[b * T_LEN + t]);
            hv = fmaf(A, hv, fmaf(xv, fwg, fbg));
            float y = hv * wo;
            y += __shfl_xor(y, 1, 64);
            y += __shfl_xor(y, 2, 64);
            y += __shfl_xor(y, 4, 64);
            y += __shfl_xor(y, 8, 64);
            y += __shfl_xor(y, 16, 64);
            if (tt == h) ykeep = y + ob;
        }
        int oidx = b * T_LEN + t0 + blk * 32 + h;
        if (isbf) outb[oidx] = f2bf(ykeep);
        else      outf[oidx] = ykeep;
    }
}

extern "C" void kernel_launch(void* const* d_in, const int* in_sizes, int n_in,
                              void* d_out, int out_size, void* d_ws, size_t ws_size,
                              hipStream_t stream)
{
    ushort_t* cv = (ushort_t*)d_ws;
    const ushort_t* x    = cv + OFF_X;
    const ushort_t* fcw  = cv + OFF_FCW;
    const ushort_t* fcb  = cv + OFF_FCB;
    const ushort_t* wih  = cv + OFF_WIH;
    const ushort_t* whh  = cv + OFF_WHH;
    const ushort_t* bih  = cv + OFF_BIH;
    const ushort_t* bhh  = cv + OFF_BHH;
    const ushort_t* ofw  = cv + OFF_OFW;
    const ushort_t* ofb  = cv + OFF_OFB;
    const ushort_t* finw = cv + OFF_FINW;
    const ushort_t* finb = cv + OFF_FINB;
    const ushort_t* fow  = cv + OFF_FOW;
    const ushort_t* fob  = cv + OFF_FOB;

    float* Aslow = (float*)((char*)d_ws + CONV_PAD_BYTES);  // 8192*32 f32
    float* gslow = Aslow + 8192 * 32;
    float* P     = gslow + 8192 * 32;          // 4*32*NCH
    float* S     = P + 4 * 32 * NCH;
    float* Hpre  = S + 4 * 32 * NCH;
    int*   flag  = (int*)(Hpre + 4 * 32 * NCH);

    Ptrs13 ptrs;
    for (int i = 0; i < 13; ++i) ptrs.p[i] = d_in[i];

    convert_kernel<<<dim3(920), dim3(256), 0, stream>>>(ptrs, flag, cv);
    gru_kernel<<<dim3(512), dim3(256), 0, stream>>>(
        x, fcw, fcb, wih, whh, bih, bhh, ofw, ofb, Aslow, gslow);
    pass1_kernel<<<dim3(128), dim3(256), 0, stream>>>(
        x, Aslow, gslow, finw, finb, P, S);
    scan_kernel<<<dim3(1), dim3(128), 0, stream>>>(P, S, Hpre);
    pass2_kernel<<<dim3(128), dim3(256), 0, stream>>>(
        x, Aslow, gslow, Hpre, finw, finb, fow, fob, flag, d_out);
}